// Round 17
// baseline (361.217 us; speedup 1.0000x reference)
//
#include <hip/hip_runtime.h>
#include <hip/hip_bf16.h>
#include <hip/hip_fp16.h>
#include <math.h>

// ---------------- constants ----------------
#define BB 16
#define CC 192
#define SHIFT 8
#define NH 6
#define DD 32
#define NN 256       // tokens per window
#define HID 768
#define NWIN 256     // B * 16 windows
#define NROWS 65536  // B * H * W tokens

// ws byte offsets
#define OFF_TBL   0ll
#define OFF_BIASM (32ll<<10)      // fp16: 4*6*256*256*2 = 3,145,728
#define OFF_WQKV  (3200ll<<10)    // 221,184
#define OFF_PWB   (3424ll<<10)    // 73,728
#define OFF_W1B   (3500ll<<10)    // 294,912
#define OFF_W2B   (3800ll<<10)    // 294,912
#define OFF_BQKV  (4096ll<<10)    // 2,304
#define OFF_WTAB  (4104ll<<10)    // 4*16*192*4 = 49,152
#define OFF_XB    (8ll<<20)       // 25,165,824 -> ends at 32MB
#define OFF_Q     (32ll<<20)
#define OFF_K     (56ll<<20)
#define OFF_V     (80ll<<20)
#define OFF_AO    (104ll<<20)     // ends 128MB
#define OFF_HB    OFF_XB          // window-layout h; in-place over XB

typedef __attribute__((ext_vector_type(4)))  float f32x4;
typedef __attribute__((ext_vector_type(16))) float f32x16;
typedef __attribute__((ext_vector_type(8)))  short bf16x8;

__device__ __forceinline__ void gload16(const void* g, void* l) {
    __builtin_amdgcn_global_load_lds(
        (const __attribute__((address_space(1))) void*)g,
        (__attribute__((address_space(3))) void*)l, 16, 0, 0);
}

__device__ __forceinline__ float b2f(short s) {
    unsigned u = ((unsigned)(unsigned short)s) << 16;
    return __builtin_bit_cast(float, u);
}
__device__ __forceinline__ short f2b(float f) {
    return __builtin_bit_cast(short, __float2bfloat16(f));
}
__device__ __forceinline__ unsigned pk2(float lo, float hi) {
    unsigned a = (unsigned short)f2b(lo);
    unsigned b = (unsigned short)f2b(hi);
    return a | (b << 16);
}

__device__ __forceinline__ float fexp2(float x) {
#if __has_builtin(__builtin_amdgcn_exp2f)
    return __builtin_amdgcn_exp2f(x);
#else
    return __expf(x * 0.69314718056f);
#endif
}

// tanh-form GELU via sigmoid: ~8 VALU ops, max abs err ~3e-4
__device__ __forceinline__ float gelu_fast(float x) {
    float x2 = x * x;
    float z = x * fmaf(0.0713548353f, x2, 1.5957691216f);
    float e = __expf(-z);
    return x * __builtin_amdgcn_rcpf(1.0f + e);
}

__device__ __forceinline__ float cpb_coord(int u) {
    float t = (float)u * (8.0f / 15.0f);
    return copysignf(log2f(fabsf(t) + 1.0f) * (1.0f / 3.0f), t);
}

// ---------------- CPB table MLP: tbl[m][h], m in [0,961) ----------------
__global__ __launch_bounds__(512) void k_tbl(
    const float* __restrict__ w1, const float* __restrict__ b1,
    const float* __restrict__ w2, float* __restrict__ tbl)
{
    __shared__ float r[512];
    int m = blockIdx.x;            // 0..960
    int a = m / 31, b = m % 31;
    float c0 = cpb_coord(a - 15);
    float c1 = cpb_coord(b - 15);
    int hd = threadIdx.x;          // 0..511
    float rv = c0 * w1[hd * 2 + 0] + c1 * w1[hd * 2 + 1] + b1[hd];
    r[hd] = fmaxf(rv, 0.0f);
    __syncthreads();
    if (hd < NH) {
        float s = 0.0f;
        for (int k = 0; k < 512; ++k) s += r[k] * w2[hd * 512 + k];
        tbl[m * NH + hd] = s;
    }
}

// ---- biasp[ty][h][i][perm(j)] = fp16( (16*sigmoid(rpb) + mask - 16 - scale_h) * log2e )
__global__ __launch_bounds__(256) void k_biasm(
    const float* __restrict__ tbl, const float* __restrict__ lscale,
    __half* __restrict__ biasp)
{
    int bid = blockIdx.x;
    int ty = bid / (NH * NN);
    int rem = bid % (NH * NN);
    int h = rem >> 8, i = rem & 255;
    int j = threadIdx.x;
    int yi = i >> 4, xi = i & 15, yj = j >> 4, xj = j & 15;
    int idx = (yi - yj + 15) * 31 + (xi - xj + 15);
    float v = 16.0f / (1.0f + __expf(-tbl[idx * NH + h]));
    int rhi = (ty & 2) ? ((yi < SHIFT) ? 1 : 2) : 0;
    int rwi = (ty & 1) ? ((xi < SHIFT) ? 1 : 2) : 0;
    int rhj = (ty & 2) ? ((yj < SHIFT) ? 1 : 2) : 0;
    int rwj = (ty & 1) ? ((xj < SHIFT) ? 1 : 2) : 0;
    if (rhi * 3 + rwi != rhj * 3 + rwj) v -= 100.0f;
    float scale = __expf(fminf(lscale[h], 4.6051702f));
    v = (v - 16.0f - scale) * 1.44269504f;
    int jc = j & 31;
    int r = (jc & 3) + 4 * (jc >> 3);
    int g = (jc >> 2) & 1;
    int pos = (j & ~31) + g * 16 + r;
    biasp[(((size_t)ty * NH + h) * NN + i) * NN + pos] = __float2half(v);
}

// ---------------- weights fp32 -> bf16 (+ qkv bias concat) ----------------
__global__ __launch_bounds__(256) void k_cvt(
    const float* __restrict__ qw, const float* __restrict__ kw,
    const float* __restrict__ vw, const float* __restrict__ pw,
    const float* __restrict__ fc1w, const float* __restrict__ fc2w,
    const float* __restrict__ q_b, const float* __restrict__ v_b,
    __hip_bfloat16* __restrict__ wqkv, __hip_bfloat16* __restrict__ pwb,
    __hip_bfloat16* __restrict__ w1b, __hip_bfloat16* __restrict__ w2b,
    float* __restrict__ bqkv)
{
    int i = blockIdx.x * 256 + threadIdx.x;
    const int S1 = 36864, S2 = 73728, S3 = 110592, S4 = 147456,
              S5 = 294912, S6 = 442368, S7 = 442944;
    if (i < S3) {
        const float* src = (i < S1) ? qw : (i < S2) ? kw : vw;
        int off = (i < S1) ? i : (i < S2) ? i - S1 : i - S2;
        wqkv[i] = __float2bfloat16(src[off]);
    } else if (i < S4) { pwb[i - S3] = __float2bfloat16(pw[i - S3]); }
    else if (i < S5)   { w1b[i - S4] = __float2bfloat16(fc1w[i - S4]); }
    else if (i < S6)   { w2b[i - S5] = __float2bfloat16(fc2w[i - S5]); }
    else if (i < S7) {
        int j = i - S6;
        bqkv[j] = (j < 192) ? q_b[j] : (j < 384) ? 0.0f : v_b[j - 384];
    }
}

// ---------------- cond-LN weight/bias tables: wtab[4][16][192] ----------------
__global__ __launch_bounds__(256) void k_wtab(
    const float* __restrict__ time,
    const float* __restrict__ w1w, const float* __restrict__ w1b_,
    const float* __restrict__ b1w, const float* __restrict__ b1b_,
    const float* __restrict__ w2w, const float* __restrict__ w2b_,
    const float* __restrict__ b2w, const float* __restrict__ b2b_,
    float* __restrict__ wtab)
{
    int idx = blockIdx.x * 256 + threadIdx.x;   // < 12288
    int t = idx / 3072, rem = idx % 3072;
    int b = rem / 192, c = rem % 192;
    float tm = time[b];
    float v;
    if (t == 0)      v = tm * w1w[c] + w1b_[c];
    else if (t == 1) v = tm * b1w[c] + b1b_[c];
    else if (t == 2) v = tm * w2w[c] + w2b_[c];
    else             v = tm * b2w[c] + b2b_[c];
    wtab[idx] = v;
}

// ---------------- roll + window-partition gather: x fp32 -> xb bf16 [65536][192] ----------------
__global__ __launch_bounds__(256) void k_gather(
    const float* __restrict__ x, __hip_bfloat16* __restrict__ xb)
{
    int idx = blockIdx.x * 256 + threadIdx.x;   // one per 4 channels
    int r = idx / 48, c4 = idx % 48;
    int win = r >> 8, n = r & 255;
    int b = win >> 4, wh = (win >> 2) & 3, ww = win & 3;
    int yi = n >> 4, xi = n & 15;
    int sy = (wh * 16 + yi + SHIFT) & 63;
    int sx = (ww * 16 + xi + SHIFT) & 63;
    float4 v = *(const float4*)&x[((size_t)b * 4096 + sy * 64 + sx) * CC + c4 * 4];
    union { short h[4]; short4 s4; } u;
    u.h[0] = f2b(v.x); u.h[1] = f2b(v.y); u.h[2] = f2b(v.z); u.h[3] = f2b(v.w);
    *(short4*)&((short*)xb)[(size_t)r * CC + c4 * 4] = u.s4;
}

// ---- swizzled stage: LDS slot (row, cb) holds global col-block cb^(row&7) ----
#define STAGE_SWZ(dstLds, srcPtr, ldK, nR)                                  \
    for (int r_ = 0; r_ < (nR); ++r_) {                                     \
        int off_ = r_ * 256 + tid;                                          \
        int row_ = off_ >> 3, cb_ = off_ & 7;                               \
        int ce_ = ((cb_ ^ (row_ & 7)) << 3);                                \
        gload16((srcPtr) + (size_t)row_ * (ldK) + ce_, &(dstLds)[off_ * 8]); \
    }

// ---------------- QKV MFMA GEMM + fused q/k head-norm; swizzled LDS (R12 version) ----------------
__global__ __launch_bounds__(256) void k_qkvgemm(
    const __hip_bfloat16* __restrict__ A, const __hip_bfloat16* __restrict__ Bw,
    const float* __restrict__ bias, const float* __restrict__ lscale,
    __hip_bfloat16* __restrict__ qbo, __hip_bfloat16* __restrict__ kbo,
    __hip_bfloat16* __restrict__ vbo)
{
    __shared__ short lds[12288];      // As[8192] + Bs[4096]; epilogue tile 128x64 in [0:8192]
    short* As = lds;
    short* Bs = lds + 8192;
    int tid = threadIdx.x, lane = tid & 63;
    int w = tid >> 6, wr = w >> 1, wc = w & 1;
    int bm = blockIdx.x, bn = blockIdx.y;

    f32x4 acc[4][2];
    #pragma unroll
    for (int fm = 0; fm < 4; ++fm)
        #pragma unroll
        for (int fn = 0; fn < 2; ++fn) acc[fm][fn] = (f32x4)0.0f;

    for (int kt = 0; kt < CC; kt += 64) {
        STAGE_SWZ(As, A + (size_t)(bm * 128) * CC + kt, CC, 4)
        STAGE_SWZ(Bs, Bw + (size_t)(bn * 64) * CC + kt, CC, 2)
        __syncthreads();
        #pragma unroll
        for (int kk = 0; kk < 2; ++kk) {
            int kcq = kk * 4 + (lane >> 4);
            bf16x8 af[4], bfr[2];
            #pragma unroll
            for (int fm = 0; fm < 4; ++fm) {
                int row = wr * 64 + fm * 16 + (lane & 15);
                af[fm] = *(const bf16x8*)&As[row * 64 + ((kcq ^ (row & 7)) << 3)];
            }
            #pragma unroll
            for (int fn = 0; fn < 2; ++fn) {
                int row = wc * 32 + fn * 16 + (lane & 15);
                bfr[fn] = *(const bf16x8*)&Bs[row * 64 + ((kcq ^ (row & 7)) << 3)];
            }
            #pragma unroll
            for (int fm = 0; fm < 4; ++fm)
                #pragma unroll
                for (int fn = 0; fn < 2; ++fn)
                    acc[fm][fn] = __builtin_amdgcn_mfma_f32_16x16x32_bf16(
                        af[fm], bfr[fn], acc[fm][fn], 0, 0, 0);
        }
        __syncthreads();
    }

    bool donorm = (bn < 6);
    bool isq = (bn < 3);
    float qscale = __expf(fminf(lscale[(bn % 3) * 2 + wc], 4.6051702f)) * 1.44269504f;
    int bcol = bn * 64 + wc * 32 + (lane & 15);
    // bias + norm -> swizzled LDS tile [128][64]
    #pragma unroll
    for (int fm = 0; fm < 4; ++fm)
        #pragma unroll
        for (int r = 0; r < 4; ++r) {
            float v0 = acc[fm][0][r] + bias[bcol];
            float v1 = acc[fm][1][r] + bias[bcol + 16];
            if (donorm) {
                float s2 = v0 * v0 + v1 * v1;
                s2 += __shfl_xor(s2, 1);
                s2 += __shfl_xor(s2, 2);
                s2 += __shfl_xor(s2, 4);
                s2 += __shfl_xor(s2, 8);
                float rn = rsqrtf(s2);
                if (isq) rn *= qscale;
                v0 *= rn; v1 *= rn;
            }
            int rowl = wr * 64 + fm * 16 + ((lane >> 4) << 2) + r;
            int c0 = wc * 32 + (lane & 15);
            int sw = (rowl & 3) << 4;
            lds[rowl * 64 + (c0 ^ sw)] = f2b(v0);
            lds[rowl * 64 + ((c0 + 16) ^ sw)] = f2b(v1);
        }
    __syncthreads();
    // vectorized copy-out: 4 threads/row, 16 shorts each, 2 passes
    __hip_bfloat16* dst = (bn < 3) ? qbo : (bn < 6) ? kbo : vbo;
    int cb0 = (bn % 3) * 64;
    #pragma unroll
    for (int rr = 0; rr < 2; ++rr) {
        int row = rr * 64 + (tid >> 2);
        int cl = (tid & 3) * 16;
        int cp = cl ^ ((row & 3) << 4);
        bf16x8 a = *(const bf16x8*)&lds[row * 64 + cp];
        bf16x8 b = *(const bf16x8*)&lds[row * 64 + cp + 8];
        size_t base = (size_t)(bm * 128 + row) * CC + cb0 + cl;
        *(bf16x8*)&dst[base] = a;
        *(bf16x8*)&dst[base + 8] = b;
    }
}

// ---------------- MFMA attention: per-fj restructure, exp2-folded bias ----------------
#define VTP 260
__global__ __launch_bounds__(256, 3) void k_attn(
    const __hip_bfloat16* __restrict__ qb,
    const __hip_bfloat16* __restrict__ kb,
    const __hip_bfloat16* __restrict__ vb,
    const __half* __restrict__ biasp,
    __hip_bfloat16* __restrict__ ao)
{
    __shared__ short Vt[32 * VTP];
    int blk = blockIdx.x;
    int win = blk / NH, h = blk % NH;
    int wwh = (win >> 2) & 3, www = win & 3;
    int ty = (((wwh == 3) ? 2 : 0) | ((www == 3) ? 1 : 0));
    int tid = threadIdx.x;
    int wv = tid >> 6, lane = tid & 63;
    int c = lane & 31, g = lane >> 5;

    // ---- stage V transposed: Vt[d][j] ----
    {
        int j = wv * 64 + lane;
        const short* vsrc = (const short*)vb + ((size_t)(win * NN + j)) * CC + h * DD;
        #pragma unroll
        for (int q4 = 0; q4 < 4; ++q4) {
            bf16x8 t = *(const bf16x8*)(vsrc + q4 * 8);
            #pragma unroll
            for (int e = 0; e < 8; ++e)
                Vt[(q4 * 8 + e) * VTP + j] = t[e];
        }
    }
    __syncthreads();

    // ---- Q B-frags (held in regs for all tiles) ----
    const short* qsrc = (const short*)qb + ((size_t)(win * NN + wv * 64)) * CC + h * DD;
    bf16x8 qf[2][2];
    #pragma unroll
    for (int fq = 0; fq < 2; ++fq)
        #pragma unroll
        for (int kd = 0; kd < 2; ++kd)
            qf[fq][kd] = *(const bf16x8*)(qsrc + (size_t)(32 * fq + c) * CC + 16 * kd + 8 * g);

    f32x16 acc_o[2];
    acc_o[0] = (f32x16)0.0f; acc_o[1] = (f32x16)0.0f;
    float lsum[2] = {0.0f, 0.0f};

    const short* kbase = (const short*)kb + ((size_t)(win * NN)) * CC + h * DD;
    const __half* bbase = biasp + (((size_t)ty * NH + h) * NN) * NN;

    for (int t = 0; t < 4; ++t) {
        int jt = t * 64;
        #pragma unroll
        for (int fj = 0; fj < 2; ++fj) {
            int jb = jt + 32 * fj;
            bf16x8 kf0 = *(const bf16x8*)(kbase + (size_t)(jb + c) * CC + 8 * g);
            bf16x8 kf1 = *(const bf16x8*)(kbase + (size_t)(jb + c) * CC + 16 + 8 * g);
            f32x16 st[2];
            __builtin_amdgcn_s_setprio(1);
            {
                f32x16 t0 = __builtin_amdgcn_mfma_f32_32x32x16_bf16(
                    kf0, qf[0][0], (f32x16)0.0f, 0, 0, 0);
                st[0] = __builtin_amdgcn_mfma_f32_32x32x16_bf16(
                    kf1, qf[0][1], t0, 0, 0, 0);
                f32x16 t1 = __builtin_amdgcn_mfma_f32_32x32x16_bf16(
                    kf0, qf[1][0], (f32x16)0.0f, 0, 0, 0);
                st[1] = __builtin_amdgcn_mfma_f32_32x32x16_bf16(
                    kf1, qf[1][1], t1, 0, 0, 0);
            }
            __builtin_amdgcn_s_setprio(0);
            bf16x8 vfr[2];
            #pragma unroll
            for (int rb = 0; rb < 2; ++rb) {
                int j0 = jb + 16 * rb + 4 * g;
                uint2 va = *(const uint2*)&Vt[c * VTP + j0];
                uint2 vb2 = *(const uint2*)&Vt[c * VTP + j0 + 8];
                union { unsigned u[4]; bf16x8 v; } vu;
                vu.u[0] = va.x; vu.u[1] = va.y; vu.u[2] = vb2.x; vu.u[3] = vb2.y;
                vfr[rb] = vu.v;
            }
            #pragma unroll
            for (int fq = 0; fq < 2; ++fq) {
                const __half* bp = bbase + (size_t)(wv * 64 + 32 * fq + c) * NN
                                   + jb + g * 16;
                union { uint4 u; __half2 h2[4]; } ba, bbu;
                ba.u  = *(const uint4*)bp;
                bbu.u = *(const uint4*)(bp + 8);
                float p[16];
                #pragma unroll
                for (int q4 = 0; q4 < 4; ++q4) {
                    float2 fa = __half22float2(ba.h2[q4]);
                    p[2 * q4 + 0] = st[fq][2 * q4 + 0] + fa.x;
                    p[2 * q4 + 1] = st[fq][2 * q4 + 1] + fa.y;
                    float2 fb = __half22float2(bbu.h2[q4]);
                    p[8 + 2 * q4 + 0] = st[fq][8 + 2 * q4 + 0] + fb.x;
                    p[8 + 2 * q4 + 1] = st[fq][8 + 2 * q4 + 1] + fb.y;
                }
                #pragma unroll
                for (int r = 0; r < 16; ++r) p[r] = fexp2(p[r]);
                #pragma unroll
                for (int r = 0; r < 16; ++r) lsum[fq] += p[r];
                union { unsigned u[4]; bf16x8 v; } pu0, pu1;
                pu0.u[0] = pk2(p[0],  p[1]);  pu0.u[1] = pk2(p[2],  p[3]);
                pu0.u[2] = pk2(p[4],  p[5]);  pu0.u[3] = pk2(p[6],  p[7]);
                pu1.u[0] = pk2(p[8],  p[9]);  pu1.u[1] = pk2(p[10], p[11]);
                pu1.u[2] = pk2(p[12], p[13]); pu1.u[3] = pk2(p[14], p[15]);
                __builtin_amdgcn_s_setprio(1);
                acc_o[fq] = __builtin_amdgcn_mfma_f32_32x32x16_bf16(
                    pu0.v, vfr[0], acc_o[fq], 0, 0, 0);
                acc_o[fq] = __builtin_amdgcn_mfma_f32_32x32x16_bf16(
                    pu1.v, vfr[1], acc_o[fq], 0, 0, 0);
                __builtin_amdgcn_s_setprio(0);
            }
        }
    }

    // ---- normalize + write ----
    #pragma unroll
    for (int fq = 0; fq < 2; ++fq) {
        lsum[fq] += __shfl_xor(lsum[fq], 32);
        float rlv = 1.0f / lsum[fq];
        #pragma unroll
        for (int r = 0; r < 16; ++r) {
            int rho = (r & 3) + 8 * (r >> 2) + 4 * g;
            float rli = __shfl(rlv, rho);
            int row = wv * 64 + 32 * fq + rho;
            ao[((size_t)(win * NN + row)) * CC + h * DD + c] =
                __float2bfloat16(acc_o[fq][r] * rli);
        }
    }
}

// ---------------- proj GEMM (BM=128) + cond-LN1 + bf16 residual, window layout, in-place ----------------
__global__ __launch_bounds__(256) void k_projgemm(
    const __hip_bfloat16* __restrict__ ao,
    const __hip_bfloat16* __restrict__ pwb,
    const float* __restrict__ pbias,
    const float* __restrict__ wtab,
    __hip_bfloat16* xbhb)                    // read residual + write h, same buffer
{
    __shared__ short lds[25600];             // stage: As[8192]+Bs[12288]; epilogue [128][200]
    __shared__ float part[128][4];
    short* As = lds;
    short* Bs = lds + 8192;
    int tid = threadIdx.x, lane = tid & 63;
    int w = tid >> 6, wr = w >> 1, wc = w & 1;
    int bm = blockIdx.x;                     // 512 blocks of 128 rows

    f32x4 acc[4][6];
    #pragma unroll
    for (int fm = 0; fm < 4; ++fm)
        #pragma unroll
        for (int fn = 0; fn < 6; ++fn) acc[fm][fn] = (f32x4)0.0f;

    for (int kt = 0; kt < CC; kt += 64) {
        STAGE_SWZ(As, ao + (size_t)(bm * 128) * CC + kt, CC, 4)
        STAGE_SWZ(Bs, pwb + kt, CC, 6)
        __syncthreads();
        #pragma unroll
        for (int kk = 0; kk < 2; ++kk) {
            int kcq = kk * 4 + (lane >> 4);
            bf16x8 af[4], bfr[6];
            #pragma unroll
            for (int fm = 0; fm < 4; ++fm) {
                int row = wr * 64 + fm * 16 + (lane & 15);
                af[fm] = *(const bf16x8*)&As[row * 64 + ((kcq ^ (row & 7)) << 3)];
            }
            #pragma unroll
            for (int fn = 0; fn < 6; ++fn) {
                int row = wc * 96 + fn * 16 + (lane & 15);
                bfr[fn] = *(const bf16x8*)&Bs[row * 64 + ((kcq ^ (row & 7)) << 3)];
            }
            #pragma unroll
            for (int fm = 0; fm < 4; ++fm)
                #pragma unroll
                for (int fn = 0; fn < 6; ++fn)
                    acc[fm][fn] = __builtin_amdgcn_mfma_f32_16x16x32_bf16(
                        af[fm], bfr[fn], acc[fm][fn], 0, 0, 0);
        }
        __syncthreads();
    }

    // bias + LN partials; values -> LDS tile [128][200] bf16
    #pragma unroll
    for (int fm = 0; fm < 4; ++fm)
        #pragma unroll
        for (int r = 0; r < 4; ++r) {
            int rowl = wr * 64 + fm * 16 + ((lane >> 4) << 2) + r;
            float s = 0.0f, s2 = 0.0f;
            #pragma unroll
            for (int fn = 0; fn < 6; ++fn) {
                int col = wc * 96 + fn * 16 + (lane & 15);
                float v = acc[fm][fn][r] + pbias[col];
                lds[rowl * 200 + col] = f2b(v);
                s += v; s2 += v * v;
            }
            #pragma unroll
            for (int m = 1; m < 16; m <<= 1) {
                s  += __shfl_xor(s, m);
                s2 += __shfl_xor(s2, m);
            }
            if ((lane & 15) == 0) {
                part[rowl][wc * 2]     = s;
                part[rowl][wc * 2 + 1] = s2;
            }
        }
    __syncthreads();

    // vectorized copy-out: 2 threads/row, 96 cols each
    int row = tid >> 1;
    int cb = (tid & 1) * 96;
    float s  = part[row][0] + part[row][2];
    float s2 = part[row][1] + part[row][3];
    float mean = s * (1.0f / 192.0f);
    float rstd = rsqrtf(s2 * (1.0f / 192.0f) - mean * mean + 1e-5f);
    int rw = bm * 128 + row;
    const float* wt = wtab + (rw >> 12) * 192;            // LN1 w table
    const float* bt = wtab + 16 * 192 + (rw >> 12) * 192; // LN1 b table
    #pragma unroll
    for (int c8 = 0; c8 < 12; ++c8) {
        int c = cb + c8 * 8;
        bf16x8 lv = *(const bf16x8*)&lds[row * 200 + c];
        bf16x8 xv = *(const bf16x8*)&xbhb[(size_t)rw * CC + c];
        float4 w0 = *(const float4*)&wt[c], w1 = *(const float4*)&wt[c + 4];
        float4 b0 = *(const float4*)&bt[c], b1 = *(const float4*)&bt[c + 4];
        float wv[8] = {w0.x, w0.y, w0.z, w0.w, w1.x, w1.y, w1.z, w1.w};
        float bv[8] = {b0.x, b0.y, b0.z, b0.w, b1.x, b1.y, b1.z, b1.w};
        bf16x8 o;
        #pragma unroll
        for (int e = 0; e < 8; ++e) {
            float xn = (b2f(lv[e]) - mean) * rstd;
            o[e] = f2b(b2f(xv[e]) + wv[e] * xn + bv[e]);
        }
        *(bf16x8*)&xbhb[(size_t)rw * CC + c] = o;
    }
}

// ---------------- FUSED MLP v2: A in regs, W from L2, H2 double-buffered LDS ----------------
// 64 rows/block, 1 barrier/iter, 27 KB LDS -> 3 blocks/CU.
__global__ __launch_bounds__(256, 3) void k_mlp(
    const __hip_bfloat16* __restrict__ hb,     // [65536][192] window rows
    const __hip_bfloat16* __restrict__ w1b,    // [768][192]
    const float* __restrict__ b1,
    const __hip_bfloat16* __restrict__ w2b,    // [192][768]
    const float* __restrict__ b2,
    const float* __restrict__ wtab,
    float* __restrict__ out)
{
    __shared__ short lds[12800];               // H2c[2][64][64]=16KB; epilogue VAL[64][200]=25.6KB
    __shared__ float part[64][4];
    short* H2c = lds;                          // two 4096-short buffers
    short* VAL = lds;                          // aliases (used after final barrier)

    int tid = threadIdx.x, lane = tid & 63;
    int w = tid >> 6, wr = w >> 1, wc = w & 1;
    int bm = blockIdx.x;                       // 1024 blocks of 64 rows
    size_t rb = (size_t)bm * 64;

    const short* hsrc = (const short*)hb;
    const short* w1s = (const short*)w1b;
    const short* w2s = (const short*)w2b;

    // ---- preload A-fragments once (reused by all 12 iterations): 48 VGPR ----
    bf16x8 afr[3][2][2];                       // [kt][kk][fm]
    #pragma unroll
    for (int kt = 0; kt < 3; ++kt)
        #pragma unroll
        for (int kk = 0; kk < 2; ++kk)
            #pragma unroll
            for (int fm = 0; fm < 2; ++fm) {
                int row = wr * 32 + fm * 16 + (lane & 15);
                int kof = kt * 64 + kk * 32 + (lane >> 4) * 8;
                afr[kt][kk][fm] = *(const bf16x8*)(hsrc + (rb + row) * CC + kof);
            }

    f32x4 acc2[2][6];
    #pragma unroll
    for (int fm = 0; fm < 2; ++fm)
        #pragma unroll
        for (int fn = 0; fn < 6; ++fn) acc2[fm][fn] = (f32x4)0.0f;

    int buf = 0;
    for (int it = 0; it < 12; ++it) {
        // ---- fc1: A from regs, W1 frags from global (L2-resident) ----
        f32x4 acc1[2][2];
        #pragma unroll
        for (int fm = 0; fm < 2; ++fm)
            #pragma unroll
            for (int fn = 0; fn < 2; ++fn) acc1[fm][fn] = (f32x4)0.0f;
        #pragma unroll
        for (int kt = 0; kt < 3; ++kt)
            #pragma unroll
            for (int kk = 0; kk < 2; ++kk) {
                bf16x8 bfr[2];
                #pragma unroll
                for (int fn = 0; fn < 2; ++fn) {
                    int row = it * 64 + wc * 32 + fn * 16 + (lane & 15);
                    int kof = kt * 64 + kk * 32 + (lane >> 4) * 8;
                    bfr[fn] = *(const bf16x8*)(w1s + (size_t)row * CC + kof);
                }
                #pragma unroll
                for (int fm = 0; fm < 2; ++fm)
                    #pragma unroll
                    for (int fn = 0; fn < 2; ++fn)
                        acc1[fm][fn] = __builtin_amdgcn_mfma_f32_16x16x32_bf16(
                            afr[kt][kk][fm], bfr[fn], acc1[fm][fn], 0, 0, 0);
            }
        // ---- bias + gelu -> H2c[buf] (swizzled for fc2 A-frag reads) ----
        #pragma unroll
        for (int fm = 0; fm < 2; ++fm)
            #pragma unroll
            for (int fn = 0; fn < 2; ++fn) {
                int coll = wc * 32 + fn * 16 + (lane & 15);
                float bv = b1[it * 64 + coll];
                #pragma unroll
                for (int r = 0; r < 4; ++r) {
                    int rowl = wr * 32 + fm * 16 + ((lane >> 4) << 2) + r;
                    float v = gelu_fast(acc1[fm][fn][r] + bv);
                    H2c[buf * 4096 + rowl * 64 +
                        (((coll >> 3) ^ (rowl & 7)) << 3) + (coll & 7)] = f2b(v);
                }
            }
        __syncthreads();   // H2c[buf] visible; also guards reuse of H2c[buf] two iters later

        // ---- fc2 accumulate: H2 from LDS, W2 frags from global (L2-resident) ----
        #pragma unroll
        for (int kk = 0; kk < 2; ++kk) {
            int kcq = kk * 4 + (lane >> 4);
            bf16x8 af[2], bfr[6];
            #pragma unroll
            for (int fm = 0; fm < 2; ++fm) {
                int row = wr * 32 + fm * 16 + (lane & 15);
                af[fm] = *(const bf16x8*)&H2c[buf * 4096 + row * 64 + ((kcq ^ (row & 7)) << 3)];
            }
            #pragma unroll
            for (int fn = 0; fn < 6; ++fn) {
                int row = wc * 96 + fn * 16 + (lane & 15);
                int kof = it * 64 + kk * 32 + (lane >> 4) * 8;
                bfr[fn] = *(const bf16x8*)(w2s + (size_t)row * HID + kof);
            }
            #pragma unroll
            for (int fm = 0; fm < 2; ++fm)
                #pragma unroll
                for (int fn = 0; fn < 6; ++fn)
                    acc2[fm][fn] = __builtin_amdgcn_mfma_f32_16x16x32_bf16(
                        af[fm], bfr[fn], acc2[fm][fn], 0, 0, 0);
        }
        buf ^= 1;
    }
    __syncthreads();   // all fc2 reads done before epilogue overwrites LDS

    // ---- epilogue: bias + LN partials; values -> VAL[64][200] ----
    #pragma unroll
    for (int fm = 0; fm < 2; ++fm)
        #pragma unroll
        for (int r = 0; r < 4; ++r) {
            int rowl = wr * 32 + fm * 16 + ((lane >> 4) << 2) + r;
            float s = 0.0f, s2 = 0.0f;
            #pragma unroll
            for (int fn = 0; fn < 6; ++fn) {
                int col = wc * 96 + fn * 16 + (lane & 15);
                float v = acc2[fm][fn][r] + b2[col];
                VAL[rowl * 200 + col] = f2b(v);
                s += v; s2 += v * v;
            }
            #pragma unroll
            for (int m = 1; m < 16; m <<= 1) {
                s  += __shfl_xor(s, m);
                s2 += __shfl_xor(s2, m);
            }
            if ((lane & 15) == 0) {
                part[rowl][wc * 2]     = s;
                part[rowl][wc * 2 + 1] = s2;
            }
        }
    __syncthreads();

    // ---- copy-out with residual (from global hb) + window-reverse: 4 threads/row ----
    int row = tid >> 2;
    int cb = (tid & 3) * 48;
    float s  = part[row][0] + part[row][2];
    float s2 = part[row][1] + part[row][3];
    float mean = s * (1.0f / 192.0f);
    float rstd = rsqrtf(s2 * (1.0f / 192.0f) - mean * mean + 1e-5f);
    int rw = (int)rb + row;
    int win = rw >> 8, n = rw & 255, b = rw >> 12;
    int wh = (win >> 2) & 3, wwn = win & 3;
    int y  = (wh * 16 + (n >> 4) + SHIFT) & 63;
    int xq = (wwn * 16 + (n & 15) + SHIFT) & 63;
    size_t rimg = (size_t)b * 4096 + y * 64 + xq;
    const float* wt = wtab + 2 * 16 * 192 + b * 192;   // LN2 w table
    const float* bt = wtab + 3 * 16 * 192 + b * 192;   // LN2 b table
    #pragma unroll
    for (int c8 = 0; c8 < 6; ++c8) {
        int c = cb + c8 * 8;
        bf16x8 lv = *(const bf16x8*)&VAL[row * 200 + c];
        bf16x8 hv = *(const bf16x8*)(hsrc + (size_t)rw * CC + c);
        float4 w0 = *(const float4*)&wt[c], w1 = *(const float4*)&wt[c + 4];
        float4 b0 = *(const float4*)&bt[c], b1 = *(const float4*)&bt[c + 4];
        float wv[8] = {w0.x, w0.y, w0.z, w0.w, w1.x, w1.y, w1.z, w1.w};
        float bv[8] = {b0.x, b0.y, b0.z, b0.w, b1.x, b1.y, b1.z, b1.w};
        float4 o0, o1;
        float oo[8];
        #pragma unroll
        for (int e = 0; e < 8; ++e) {
            float xn = (b2f(lv[e]) - mean) * rstd;
            oo[e] = b2f(hv[e]) + wv[e] * xn + bv[e];
        }
        o0.x = oo[0]; o0.y = oo[1]; o0.z = oo[2]; o0.w = oo[3];
        o1.x = oo[4]; o1.y = oo[5]; o1.z = oo[6]; o1.w = oo[7];
        *(float4*)&out[rimg * CC + c] = o0;
        *(float4*)&out[rimg * CC + c + 4] = o1;
    }
}

extern "C" void kernel_launch(void* const* d_in, const int* in_sizes, int n_in,
                              void* d_out, int out_size, void* d_ws, size_t ws_size,
                              hipStream_t stream)
{
    const float* x        = (const float*)d_in[0];
    const float* time     = (const float*)d_in[1];
    const float* q_w      = (const float*)d_in[2];
    const float* q_b      = (const float*)d_in[3];
    const float* k_w      = (const float*)d_in[4];
    const float* v_w      = (const float*)d_in[5];
    const float* v_b      = (const float*)d_in[6];
    const float* lscale   = (const float*)d_in[7];
    const float* cpb_w1   = (const float*)d_in[8];
    const float* cpb_b1   = (const float*)d_in[9];
    const float* cpb_w2   = (const float*)d_in[10];
    const float* proj_w   = (const float*)d_in[11];
    const float* proj_b   = (const float*)d_in[12];
    const float* ln1_ww   = (const float*)d_in[13];
    const float* ln1_wb   = (const float*)d_in[14];
    const float* ln1_bw   = (const float*)d_in[15];
    const float* ln1_bb   = (const float*)d_in[16];
    const float* fc1_w    = (const float*)d_in[17];
    const float* fc1_b    = (const float*)d_in[18];
    const float* fc2_w    = (const float*)d_in[19];
    const float* fc2_b    = (const float*)d_in[20];
    const float* ln2_ww   = (const float*)d_in[21];
    const float* ln2_wb   = (const float*)d_in[22];
    const float* ln2_bw   = (const float*)d_in[23];
    const float* ln2_bb   = (const float*)d_in[24];

    char* ws = (char*)d_ws;
    float* tbl            = (float*)(ws + OFF_TBL);
    __half* biasp         = (__half*)(ws + OFF_BIASM);
    __hip_bfloat16* wqkv  = (__hip_bfloat16*)(ws + OFF_WQKV);
    __hip_bfloat16* pwb   = (__hip_bfloat16*)(ws + OFF_PWB);
    __hip_bfloat16* w1b   = (__hip_bfloat16*)(ws + OFF_W1B);
    __hip_bfloat16* w2b   = (__hip_bfloat16*)(ws + OFF_W2B);
    float* bqkv           = (float*)(ws + OFF_BQKV);
    float* wtab           = (float*)(ws + OFF_WTAB);
    __hip_bfloat16* xb    = (__hip_bfloat16*)(ws + OFF_XB);
    __hip_bfloat16* qb    = (__hip_bfloat16*)(ws + OFF_Q);
    __hip_bfloat16* kb    = (__hip_bfloat16*)(ws + OFF_K);
    __hip_bfloat16* vb    = (__hip_bfloat16*)(ws + OFF_V);
    __hip_bfloat16* ao    = (__hip_bfloat16*)(ws + OFF_AO);
    __hip_bfloat16* hb    = (__hip_bfloat16*)(ws + OFF_HB);   // == xb region
    float* out            = (float*)d_out;

    k_tbl   <<<961, 512, 0, stream>>>(cpb_w1, cpb_b1, cpb_w2, tbl);
    k_biasm <<<4 * NH * NN, 256, 0, stream>>>(tbl, lscale, biasp);
    k_cvt   <<<1731, 256, 0, stream>>>(q_w, k_w, v_w, proj_w, fc1_w, fc2_w,
                                       q_b, v_b, wqkv, pwb, w1b, w2b, bqkv);
    k_wtab  <<<48, 256, 0, stream>>>(time, ln1_ww, ln1_wb, ln1_bw, ln1_bb,
                                     ln2_ww, ln2_wb, ln2_bw, ln2_bb, wtab);
    k_gather<<<12288, 256, 0, stream>>>(x, xb);
    k_qkvgemm<<<dim3(NROWS / 128, 9), 256, 0, stream>>>(xb, wqkv, bqkv, lscale, qb, kb, vb);
    k_attn  <<<NWIN * NH, 256, 0, stream>>>(qb, kb, vb, biasp, ao);
    k_projgemm<<<NROWS / 128, 256, 0, stream>>>(ao, pwb, proj_b, wtab, xb);
    k_mlp   <<<NROWS / 64, 256, 0, stream>>>(hb, w1b, fc1_b, w2b, fc2_b, wtab, out);
}

// Round 18
// 230.265 us; speedup vs baseline: 1.5687x; 1.5687x over previous
//
#include <hip/hip_runtime.h>
#include <hip/hip_bf16.h>
#include <hip/hip_fp16.h>
#include <math.h>

// ---------------- constants ----------------
#define BB 16
#define CC 192
#define SHIFT 8
#define NH 6
#define DD 32
#define NN 256       // tokens per window
#define HID 768
#define NWIN 256     // B * 16 windows
#define NROWS 65536  // B * H * W tokens

// ws byte offsets
#define OFF_TBL   0ll
#define OFF_BIASM (32ll<<10)      // fp16: 4*6*256*256*2 = 3,145,728
#define OFF_WQKV  (3200ll<<10)    // 221,184
#define OFF_PWB   (3424ll<<10)    // 73,728
#define OFF_W1B   (3500ll<<10)    // 294,912
#define OFF_W2B   (3800ll<<10)    // 294,912
#define OFF_BQKV  (4096ll<<10)    // 2,304
#define OFF_WTAB  (4104ll<<10)    // 4*16*192*4 = 49,152
#define OFF_XB    (8ll<<20)       // 25,165,824 -> ends at 32MB
#define OFF_Q     (32ll<<20)
#define OFF_K     (56ll<<20)
#define OFF_V     (80ll<<20)
#define OFF_AO    (104ll<<20)     // ends 128MB
#define OFF_HB    OFF_XB          // window-layout h; in-place over XB

typedef __attribute__((ext_vector_type(4)))  float f32x4;
typedef __attribute__((ext_vector_type(16))) float f32x16;
typedef __attribute__((ext_vector_type(8)))  short bf16x8;

__device__ __forceinline__ void gload16(const void* g, void* l) {
    __builtin_amdgcn_global_load_lds(
        (const __attribute__((address_space(1))) void*)g,
        (__attribute__((address_space(3))) void*)l, 16, 0, 0);
}

__device__ __forceinline__ float b2f(short s) {
    unsigned u = ((unsigned)(unsigned short)s) << 16;
    return __builtin_bit_cast(float, u);
}
__device__ __forceinline__ short f2b(float f) {
    return __builtin_bit_cast(short, __float2bfloat16(f));
}
__device__ __forceinline__ unsigned pk2(float lo, float hi) {
    unsigned a = (unsigned short)f2b(lo);
    unsigned b = (unsigned short)f2b(hi);
    return a | (b << 16);
}

__device__ __forceinline__ float fexp2(float x) {
#if __has_builtin(__builtin_amdgcn_exp2f)
    return __builtin_amdgcn_exp2f(x);
#else
    return __expf(x * 0.69314718056f);
#endif
}

// tanh-form GELU via sigmoid: ~8 VALU ops, max abs err ~3e-4
__device__ __forceinline__ float gelu_fast(float x) {
    float x2 = x * x;
    float z = x * fmaf(0.0713548353f, x2, 1.5957691216f);
    float e = __expf(-z);
    return x * __builtin_amdgcn_rcpf(1.0f + e);
}

__device__ __forceinline__ float cpb_coord(int u) {
    float t = (float)u * (8.0f / 15.0f);
    return copysignf(log2f(fabsf(t) + 1.0f) * (1.0f / 3.0f), t);
}

// ---------------- CPB table MLP: tbl[m][h], m in [0,961) ----------------
__global__ __launch_bounds__(512) void k_tbl(
    const float* __restrict__ w1, const float* __restrict__ b1,
    const float* __restrict__ w2, float* __restrict__ tbl)
{
    __shared__ float r[512];
    int m = blockIdx.x;            // 0..960
    int a = m / 31, b = m % 31;
    float c0 = cpb_coord(a - 15);
    float c1 = cpb_coord(b - 15);
    int hd = threadIdx.x;          // 0..511
    float rv = c0 * w1[hd * 2 + 0] + c1 * w1[hd * 2 + 1] + b1[hd];
    r[hd] = fmaxf(rv, 0.0f);
    __syncthreads();
    if (hd < NH) {
        float s = 0.0f;
        for (int k = 0; k < 512; ++k) s += r[k] * w2[hd * 512 + k];
        tbl[m * NH + hd] = s;
    }
}

// ---- biasp[ty][h][i][perm(j)] = fp16( (16*sigmoid(rpb) + mask - 16 - scale_h) * log2e )
__global__ __launch_bounds__(256) void k_biasm(
    const float* __restrict__ tbl, const float* __restrict__ lscale,
    __half* __restrict__ biasp)
{
    int bid = blockIdx.x;
    int ty = bid / (NH * NN);
    int rem = bid % (NH * NN);
    int h = rem >> 8, i = rem & 255;
    int j = threadIdx.x;
    int yi = i >> 4, xi = i & 15, yj = j >> 4, xj = j & 15;
    int idx = (yi - yj + 15) * 31 + (xi - xj + 15);
    float v = 16.0f / (1.0f + __expf(-tbl[idx * NH + h]));
    int rhi = (ty & 2) ? ((yi < SHIFT) ? 1 : 2) : 0;
    int rwi = (ty & 1) ? ((xi < SHIFT) ? 1 : 2) : 0;
    int rhj = (ty & 2) ? ((yj < SHIFT) ? 1 : 2) : 0;
    int rwj = (ty & 1) ? ((xj < SHIFT) ? 1 : 2) : 0;
    if (rhi * 3 + rwi != rhj * 3 + rwj) v -= 100.0f;
    float scale = __expf(fminf(lscale[h], 4.6051702f));
    v = (v - 16.0f - scale) * 1.44269504f;
    int jc = j & 31;
    int r = (jc & 3) + 4 * (jc >> 3);
    int g = (jc >> 2) & 1;
    int pos = (j & ~31) + g * 16 + r;
    biasp[(((size_t)ty * NH + h) * NN + i) * NN + pos] = __float2half(v);
}

// ---------------- weights fp32 -> bf16 (+ qkv bias concat) ----------------
__global__ __launch_bounds__(256) void k_cvt(
    const float* __restrict__ qw, const float* __restrict__ kw,
    const float* __restrict__ vw, const float* __restrict__ pw,
    const float* __restrict__ fc1w, const float* __restrict__ fc2w,
    const float* __restrict__ q_b, const float* __restrict__ v_b,
    __hip_bfloat16* __restrict__ wqkv, __hip_bfloat16* __restrict__ pwb,
    __hip_bfloat16* __restrict__ w1b, __hip_bfloat16* __restrict__ w2b,
    float* __restrict__ bqkv)
{
    int i = blockIdx.x * 256 + threadIdx.x;
    const int S1 = 36864, S2 = 73728, S3 = 110592, S4 = 147456,
              S5 = 294912, S6 = 442368, S7 = 442944;
    if (i < S3) {
        const float* src = (i < S1) ? qw : (i < S2) ? kw : vw;
        int off = (i < S1) ? i : (i < S2) ? i - S1 : i - S2;
        wqkv[i] = __float2bfloat16(src[off]);
    } else if (i < S4) { pwb[i - S3] = __float2bfloat16(pw[i - S3]); }
    else if (i < S5)   { w1b[i - S4] = __float2bfloat16(fc1w[i - S4]); }
    else if (i < S6)   { w2b[i - S5] = __float2bfloat16(fc2w[i - S5]); }
    else if (i < S7) {
        int j = i - S6;
        bqkv[j] = (j < 192) ? q_b[j] : (j < 384) ? 0.0f : v_b[j - 384];
    }
}

// ---------------- cond-LN weight/bias tables: wtab[4][16][192] ----------------
__global__ __launch_bounds__(256) void k_wtab(
    const float* __restrict__ time,
    const float* __restrict__ w1w, const float* __restrict__ w1b_,
    const float* __restrict__ b1w, const float* __restrict__ b1b_,
    const float* __restrict__ w2w, const float* __restrict__ w2b_,
    const float* __restrict__ b2w, const float* __restrict__ b2b_,
    float* __restrict__ wtab)
{
    int idx = blockIdx.x * 256 + threadIdx.x;   // < 12288
    int t = idx / 3072, rem = idx % 3072;
    int b = rem / 192, c = rem % 192;
    float tm = time[b];
    float v;
    if (t == 0)      v = tm * w1w[c] + w1b_[c];
    else if (t == 1) v = tm * b1w[c] + b1b_[c];
    else if (t == 2) v = tm * w2w[c] + w2b_[c];
    else             v = tm * b2w[c] + b2b_[c];
    wtab[idx] = v;
}

// ---------------- roll + window-partition gather: x fp32 -> xb bf16 [65536][192] ----------------
__global__ __launch_bounds__(256) void k_gather(
    const float* __restrict__ x, __hip_bfloat16* __restrict__ xb)
{
    int idx = blockIdx.x * 256 + threadIdx.x;   // one per 4 channels
    int r = idx / 48, c4 = idx % 48;
    int win = r >> 8, n = r & 255;
    int b = win >> 4, wh = (win >> 2) & 3, ww = win & 3;
    int yi = n >> 4, xi = n & 15;
    int sy = (wh * 16 + yi + SHIFT) & 63;
    int sx = (ww * 16 + xi + SHIFT) & 63;
    float4 v = *(const float4*)&x[((size_t)b * 4096 + sy * 64 + sx) * CC + c4 * 4];
    union { short h[4]; short4 s4; } u;
    u.h[0] = f2b(v.x); u.h[1] = f2b(v.y); u.h[2] = f2b(v.z); u.h[3] = f2b(v.w);
    *(short4*)&((short*)xb)[(size_t)r * CC + c4 * 4] = u.s4;
}

// ---- swizzled stage: LDS slot (row, cb) holds global col-block cb^(row&7) ----
#define STAGE_SWZ(dstLds, srcPtr, ldK, nR)                                  \
    for (int r_ = 0; r_ < (nR); ++r_) {                                     \
        int off_ = r_ * 256 + tid;                                          \
        int row_ = off_ >> 3, cb_ = off_ & 7;                               \
        int ce_ = ((cb_ ^ (row_ & 7)) << 3);                                \
        gload16((srcPtr) + (size_t)row_ * (ldK) + ce_, &(dstLds)[off_ * 8]); \
    }

// ---------------- QKV MFMA GEMM + fused q/k head-norm; swizzled LDS ----------------
__global__ __launch_bounds__(256) void k_qkvgemm(
    const __hip_bfloat16* __restrict__ A, const __hip_bfloat16* __restrict__ Bw,
    const float* __restrict__ bias, const float* __restrict__ lscale,
    __hip_bfloat16* __restrict__ qbo, __hip_bfloat16* __restrict__ kbo,
    __hip_bfloat16* __restrict__ vbo)
{
    __shared__ short lds[12288];      // As[8192] + Bs[4096]; epilogue tile 128x64 in [0:8192]
    short* As = lds;
    short* Bs = lds + 8192;
    int tid = threadIdx.x, lane = tid & 63;
    int w = tid >> 6, wr = w >> 1, wc = w & 1;
    int bm = blockIdx.x, bn = blockIdx.y;

    f32x4 acc[4][2];
    #pragma unroll
    for (int fm = 0; fm < 4; ++fm)
        #pragma unroll
        for (int fn = 0; fn < 2; ++fn) acc[fm][fn] = (f32x4)0.0f;

    for (int kt = 0; kt < CC; kt += 64) {
        STAGE_SWZ(As, A + (size_t)(bm * 128) * CC + kt, CC, 4)
        STAGE_SWZ(Bs, Bw + (size_t)(bn * 64) * CC + kt, CC, 2)
        __syncthreads();
        #pragma unroll
        for (int kk = 0; kk < 2; ++kk) {
            int kcq = kk * 4 + (lane >> 4);
            bf16x8 af[4], bfr[2];
            #pragma unroll
            for (int fm = 0; fm < 4; ++fm) {
                int row = wr * 64 + fm * 16 + (lane & 15);
                af[fm] = *(const bf16x8*)&As[row * 64 + ((kcq ^ (row & 7)) << 3)];
            }
            #pragma unroll
            for (int fn = 0; fn < 2; ++fn) {
                int row = wc * 32 + fn * 16 + (lane & 15);
                bfr[fn] = *(const bf16x8*)&Bs[row * 64 + ((kcq ^ (row & 7)) << 3)];
            }
            #pragma unroll
            for (int fm = 0; fm < 4; ++fm)
                #pragma unroll
                for (int fn = 0; fn < 2; ++fn)
                    acc[fm][fn] = __builtin_amdgcn_mfma_f32_16x16x32_bf16(
                        af[fm], bfr[fn], acc[fm][fn], 0, 0, 0);
        }
        __syncthreads();
    }

    bool donorm = (bn < 6);
    bool isq = (bn < 3);
    float qscale = __expf(fminf(lscale[(bn % 3) * 2 + wc], 4.6051702f)) * 1.44269504f;
    int bcol = bn * 64 + wc * 32 + (lane & 15);
    // bias + norm -> swizzled LDS tile [128][64]
    #pragma unroll
    for (int fm = 0; fm < 4; ++fm)
        #pragma unroll
        for (int r = 0; r < 4; ++r) {
            float v0 = acc[fm][0][r] + bias[bcol];
            float v1 = acc[fm][1][r] + bias[bcol + 16];
            if (donorm) {
                float s2 = v0 * v0 + v1 * v1;
                s2 += __shfl_xor(s2, 1);
                s2 += __shfl_xor(s2, 2);
                s2 += __shfl_xor(s2, 4);
                s2 += __shfl_xor(s2, 8);
                float rn = rsqrtf(s2);
                if (isq) rn *= qscale;
                v0 *= rn; v1 *= rn;
            }
            int rowl = wr * 64 + fm * 16 + ((lane >> 4) << 2) + r;
            int c0 = wc * 32 + (lane & 15);
            int sw = (rowl & 3) << 4;
            lds[rowl * 64 + (c0 ^ sw)] = f2b(v0);
            lds[rowl * 64 + ((c0 + 16) ^ sw)] = f2b(v1);
        }
    __syncthreads();
    // vectorized copy-out: 4 threads/row, 16 shorts each, 2 passes
    __hip_bfloat16* dst = (bn < 3) ? qbo : (bn < 6) ? kbo : vbo;
    int cb0 = (bn % 3) * 64;
    #pragma unroll
    for (int rr = 0; rr < 2; ++rr) {
        int row = rr * 64 + (tid >> 2);
        int cl = (tid & 3) * 16;
        int cp = cl ^ ((row & 3) << 4);
        bf16x8 a = *(const bf16x8*)&lds[row * 64 + cp];
        bf16x8 b = *(const bf16x8*)&lds[row * 64 + cp + 8];
        size_t base = (size_t)(bm * 128 + row) * CC + cb0 + cl;
        *(bf16x8*)&dst[base] = a;
        *(bf16x8*)&dst[base + 8] = b;
    }
}

// ---------------- MFMA attention: per-fj restructure, exp2-folded bias ----------------
#define VTP 260
__global__ __launch_bounds__(256, 3) void k_attn(
    const __hip_bfloat16* __restrict__ qb,
    const __hip_bfloat16* __restrict__ kb,
    const __hip_bfloat16* __restrict__ vb,
    const __half* __restrict__ biasp,
    __hip_bfloat16* __restrict__ ao)
{
    __shared__ short Vt[32 * VTP];
    int blk = blockIdx.x;
    int win = blk / NH, h = blk % NH;
    int wwh = (win >> 2) & 3, www = win & 3;
    int ty = (((wwh == 3) ? 2 : 0) | ((www == 3) ? 1 : 0));
    int tid = threadIdx.x;
    int wv = tid >> 6, lane = tid & 63;
    int c = lane & 31, g = lane >> 5;

    // ---- stage V transposed: Vt[d][j] ----
    {
        int j = wv * 64 + lane;
        const short* vsrc = (const short*)vb + ((size_t)(win * NN + j)) * CC + h * DD;
        #pragma unroll
        for (int q4 = 0; q4 < 4; ++q4) {
            bf16x8 t = *(const bf16x8*)(vsrc + q4 * 8);
            #pragma unroll
            for (int e = 0; e < 8; ++e)
                Vt[(q4 * 8 + e) * VTP + j] = t[e];
        }
    }
    __syncthreads();

    // ---- Q B-frags (held in regs for all tiles) ----
    const short* qsrc = (const short*)qb + ((size_t)(win * NN + wv * 64)) * CC + h * DD;
    bf16x8 qf[2][2];
    #pragma unroll
    for (int fq = 0; fq < 2; ++fq)
        #pragma unroll
        for (int kd = 0; kd < 2; ++kd)
            qf[fq][kd] = *(const bf16x8*)(qsrc + (size_t)(32 * fq + c) * CC + 16 * kd + 8 * g);

    f32x16 acc_o[2];
    acc_o[0] = (f32x16)0.0f; acc_o[1] = (f32x16)0.0f;
    float lsum[2] = {0.0f, 0.0f};

    const short* kbase = (const short*)kb + ((size_t)(win * NN)) * CC + h * DD;
    const __half* bbase = biasp + (((size_t)ty * NH + h) * NN) * NN;

    for (int t = 0; t < 4; ++t) {
        int jt = t * 64;
        #pragma unroll
        for (int fj = 0; fj < 2; ++fj) {
            int jb = jt + 32 * fj;
            bf16x8 kf0 = *(const bf16x8*)(kbase + (size_t)(jb + c) * CC + 8 * g);
            bf16x8 kf1 = *(const bf16x8*)(kbase + (size_t)(jb + c) * CC + 16 + 8 * g);
            f32x16 st[2];
            __builtin_amdgcn_s_setprio(1);
            {
                f32x16 t0 = __builtin_amdgcn_mfma_f32_32x32x16_bf16(
                    kf0, qf[0][0], (f32x16)0.0f, 0, 0, 0);
                st[0] = __builtin_amdgcn_mfma_f32_32x32x16_bf16(
                    kf1, qf[0][1], t0, 0, 0, 0);
                f32x16 t1 = __builtin_amdgcn_mfma_f32_32x32x16_bf16(
                    kf0, qf[1][0], (f32x16)0.0f, 0, 0, 0);
                st[1] = __builtin_amdgcn_mfma_f32_32x32x16_bf16(
                    kf1, qf[1][1], t1, 0, 0, 0);
            }
            __builtin_amdgcn_s_setprio(0);
            bf16x8 vfr[2];
            #pragma unroll
            for (int rb = 0; rb < 2; ++rb) {
                int j0 = jb + 16 * rb + 4 * g;
                uint2 va = *(const uint2*)&Vt[c * VTP + j0];
                uint2 vb2 = *(const uint2*)&Vt[c * VTP + j0 + 8];
                union { unsigned u[4]; bf16x8 v; } vu;
                vu.u[0] = va.x; vu.u[1] = va.y; vu.u[2] = vb2.x; vu.u[3] = vb2.y;
                vfr[rb] = vu.v;
            }
            #pragma unroll
            for (int fq = 0; fq < 2; ++fq) {
                const __half* bp = bbase + (size_t)(wv * 64 + 32 * fq + c) * NN
                                   + jb + g * 16;
                union { uint4 u; __half2 h2[4]; } ba, bbu;
                ba.u  = *(const uint4*)bp;
                bbu.u = *(const uint4*)(bp + 8);
                float p[16];
                #pragma unroll
                for (int q4 = 0; q4 < 4; ++q4) {
                    float2 fa = __half22float2(ba.h2[q4]);
                    p[2 * q4 + 0] = st[fq][2 * q4 + 0] + fa.x;
                    p[2 * q4 + 1] = st[fq][2 * q4 + 1] + fa.y;
                    float2 fb = __half22float2(bbu.h2[q4]);
                    p[8 + 2 * q4 + 0] = st[fq][8 + 2 * q4 + 0] + fb.x;
                    p[8 + 2 * q4 + 1] = st[fq][8 + 2 * q4 + 1] + fb.y;
                }
                #pragma unroll
                for (int r = 0; r < 16; ++r) p[r] = fexp2(p[r]);
                #pragma unroll
                for (int r = 0; r < 16; ++r) lsum[fq] += p[r];
                union { unsigned u[4]; bf16x8 v; } pu0, pu1;
                pu0.u[0] = pk2(p[0],  p[1]);  pu0.u[1] = pk2(p[2],  p[3]);
                pu0.u[2] = pk2(p[4],  p[5]);  pu0.u[3] = pk2(p[6],  p[7]);
                pu1.u[0] = pk2(p[8],  p[9]);  pu1.u[1] = pk2(p[10], p[11]);
                pu1.u[2] = pk2(p[12], p[13]); pu1.u[3] = pk2(p[14], p[15]);
                __builtin_amdgcn_s_setprio(1);
                acc_o[fq] = __builtin_amdgcn_mfma_f32_32x32x16_bf16(
                    pu0.v, vfr[0], acc_o[fq], 0, 0, 0);
                acc_o[fq] = __builtin_amdgcn_mfma_f32_32x32x16_bf16(
                    pu1.v, vfr[1], acc_o[fq], 0, 0, 0);
                __builtin_amdgcn_s_setprio(0);
            }
        }
    }

    // ---- normalize + write ----
    #pragma unroll
    for (int fq = 0; fq < 2; ++fq) {
        lsum[fq] += __shfl_xor(lsum[fq], 32);
        float rlv = 1.0f / lsum[fq];
        #pragma unroll
        for (int r = 0; r < 16; ++r) {
            int rho = (r & 3) + 8 * (r >> 2) + 4 * g;
            float rli = __shfl(rlv, rho);
            int row = wv * 64 + 32 * fq + rho;
            ao[((size_t)(win * NN + row)) * CC + h * DD + c] =
                __float2bfloat16(acc_o[fq][r] * rli);
        }
    }
}

// ---------------- proj GEMM (BM=128) + cond-LN1 + bf16 residual, window layout, in-place ----------------
__global__ __launch_bounds__(256) void k_projgemm(
    const __hip_bfloat16* __restrict__ ao,
    const __hip_bfloat16* __restrict__ pwb,
    const float* __restrict__ pbias,
    const float* __restrict__ wtab,
    __hip_bfloat16* xbhb)                    // read residual + write h, same buffer
{
    __shared__ short lds[25600];             // stage: As[8192]+Bs[12288]; epilogue [128][200]
    __shared__ float part[128][4];
    short* As = lds;
    short* Bs = lds + 8192;
    int tid = threadIdx.x, lane = tid & 63;
    int w = tid >> 6, wr = w >> 1, wc = w & 1;
    int bm = blockIdx.x;                     // 512 blocks of 128 rows

    f32x4 acc[4][6];
    #pragma unroll
    for (int fm = 0; fm < 4; ++fm)
        #pragma unroll
        for (int fn = 0; fn < 6; ++fn) acc[fm][fn] = (f32x4)0.0f;

    for (int kt = 0; kt < CC; kt += 64) {
        STAGE_SWZ(As, ao + (size_t)(bm * 128) * CC + kt, CC, 4)
        STAGE_SWZ(Bs, pwb + kt, CC, 6)
        __syncthreads();
        #pragma unroll
        for (int kk = 0; kk < 2; ++kk) {
            int kcq = kk * 4 + (lane >> 4);
            bf16x8 af[4], bfr[6];
            #pragma unroll
            for (int fm = 0; fm < 4; ++fm) {
                int row = wr * 64 + fm * 16 + (lane & 15);
                af[fm] = *(const bf16x8*)&As[row * 64 + ((kcq ^ (row & 7)) << 3)];
            }
            #pragma unroll
            for (int fn = 0; fn < 6; ++fn) {
                int row = wc * 96 + fn * 16 + (lane & 15);
                bfr[fn] = *(const bf16x8*)&Bs[row * 64 + ((kcq ^ (row & 7)) << 3)];
            }
            #pragma unroll
            for (int fm = 0; fm < 4; ++fm)
                #pragma unroll
                for (int fn = 0; fn < 6; ++fn)
                    acc[fm][fn] = __builtin_amdgcn_mfma_f32_16x16x32_bf16(
                        af[fm], bfr[fn], acc[fm][fn], 0, 0, 0);
        }
        __syncthreads();
    }

    // bias + LN partials; values -> LDS tile [128][200] bf16
    #pragma unroll
    for (int fm = 0; fm < 4; ++fm)
        #pragma unroll
        for (int r = 0; r < 4; ++r) {
            int rowl = wr * 64 + fm * 16 + ((lane >> 4) << 2) + r;
            float s = 0.0f, s2 = 0.0f;
            #pragma unroll
            for (int fn = 0; fn < 6; ++fn) {
                int col = wc * 96 + fn * 16 + (lane & 15);
                float v = acc[fm][fn][r] + pbias[col];
                lds[rowl * 200 + col] = f2b(v);
                s += v; s2 += v * v;
            }
            #pragma unroll
            for (int m = 1; m < 16; m <<= 1) {
                s  += __shfl_xor(s, m);
                s2 += __shfl_xor(s2, m);
            }
            if ((lane & 15) == 0) {
                part[rowl][wc * 2]     = s;
                part[rowl][wc * 2 + 1] = s2;
            }
        }
    __syncthreads();

    // vectorized copy-out: 2 threads/row, 96 cols each
    int row = tid >> 1;
    int cb = (tid & 1) * 96;
    float s  = part[row][0] + part[row][2];
    float s2 = part[row][1] + part[row][3];
    float mean = s * (1.0f / 192.0f);
    float rstd = rsqrtf(s2 * (1.0f / 192.0f) - mean * mean + 1e-5f);
    int rw = bm * 128 + row;
    const float* wt = wtab + (rw >> 12) * 192;            // LN1 w table
    const float* bt = wtab + 16 * 192 + (rw >> 12) * 192; // LN1 b table
    #pragma unroll
    for (int c8 = 0; c8 < 12; ++c8) {
        int c = cb + c8 * 8;
        bf16x8 lv = *(const bf16x8*)&lds[row * 200 + c];
        bf16x8 xv = *(const bf16x8*)&xbhb[(size_t)rw * CC + c];
        float4 w0 = *(const float4*)&wt[c], w1 = *(const float4*)&wt[c + 4];
        float4 b0 = *(const float4*)&bt[c], b1 = *(const float4*)&bt[c + 4];
        float wv[8] = {w0.x, w0.y, w0.z, w0.w, w1.x, w1.y, w1.z, w1.w};
        float bv[8] = {b0.x, b0.y, b0.z, b0.w, b1.x, b1.y, b1.z, b1.w};
        bf16x8 o;
        #pragma unroll
        for (int e = 0; e < 8; ++e) {
            float xn = (b2f(lv[e]) - mean) * rstd;
            o[e] = f2b(b2f(xv[e]) + wv[e] * xn + bv[e]);
        }
        *(bf16x8*)&xbhb[(size_t)rw * CC + c] = o;
    }
}

// ---------------- FUSED MLP (64 rows, R12 structure): fc1+GELU+fc2+cond-LN2+residual ----------------
__global__ __launch_bounds__(256, 2) void k_mlp(
    const __hip_bfloat16* __restrict__ hb,     // [65536][192] window rows
    const __hip_bfloat16* __restrict__ w1b,    // [768][192]
    const float* __restrict__ b1,
    const __hip_bfloat16* __restrict__ w2b,    // [192][768]
    const float* __restrict__ b2,
    const float* __restrict__ wtab,
    float* __restrict__ out)
{
    __shared__ short lds[40960];               // 80 KB
    short* As  = lds;                          // [3][64][64] persistent (GEMM A + residual)
    short* W1c = lds + 12288;                  // [3][64][64] per-iter fc1 weights
    short* H2c = lds + 24576;                  // [64][64] gelu(fc1) chunk
    short* W2c = lds + 28672;                  // [192][64] per-iter fc2 weight K-slice
    short* VAL = lds + 12288;                  // epilogue val tile [64][200] (over W1c+H2c)
    float* part = (float*)&lds[28672];         // epilogue partials [64][4] (over W2c)

    int tid = threadIdx.x, lane = tid & 63;
    int w = tid >> 6, wr = w >> 1, wc = w & 1;
    int bm = blockIdx.x;                       // 1024 blocks of 64 rows
    size_t rb = (size_t)bm * 64;

    // stage A (h rows) once: 3 swizzled [64][64] chunks
    #pragma unroll
    for (int kt = 0; kt < 3; ++kt)
        STAGE_SWZ(As + kt * 4096, hb + rb * CC + kt * 64, CC, 2)

    f32x4 acc2[2][6];
    #pragma unroll
    for (int fm = 0; fm < 2; ++fm)
        #pragma unroll
        for (int fn = 0; fn < 6; ++fn) acc2[fm][fn] = (f32x4)0.0f;

    for (int it = 0; it < 12; ++it) {
        __syncthreads();   // prev-iter fc1/fc2 reads of W1c/H2c/W2c complete
        #pragma unroll
        for (int kt = 0; kt < 3; ++kt)
            STAGE_SWZ(W1c + kt * 4096, w1b + (size_t)(it * 64) * CC + kt * 64, CC, 2)
        STAGE_SWZ(W2c, w2b + it * 64, HID, 6)
        __syncthreads();   // stages (and, on it==0, As) complete

        // ---- fc1: 64x64 tile over K=192 ----
        f32x4 acc1[2][2];
        #pragma unroll
        for (int fm = 0; fm < 2; ++fm)
            #pragma unroll
            for (int fn = 0; fn < 2; ++fn) acc1[fm][fn] = (f32x4)0.0f;
        #pragma unroll
        for (int kt = 0; kt < 3; ++kt)
            #pragma unroll
            for (int kk = 0; kk < 2; ++kk) {
                int kcq = kk * 4 + (lane >> 4);
                bf16x8 af[2], bfr[2];
                #pragma unroll
                for (int fm = 0; fm < 2; ++fm) {
                    int row = wr * 32 + fm * 16 + (lane & 15);
                    af[fm] = *(const bf16x8*)&As[kt * 4096 + row * 64 + ((kcq ^ (row & 7)) << 3)];
                }
                #pragma unroll
                for (int fn = 0; fn < 2; ++fn) {
                    int row = wc * 32 + fn * 16 + (lane & 15);
                    bfr[fn] = *(const bf16x8*)&W1c[kt * 4096 + row * 64 + ((kcq ^ (row & 7)) << 3)];
                }
                #pragma unroll
                for (int fm = 0; fm < 2; ++fm)
                    #pragma unroll
                    for (int fn = 0; fn < 2; ++fn)
                        acc1[fm][fn] = __builtin_amdgcn_mfma_f32_16x16x32_bf16(
                            af[fm], bfr[fn], acc1[fm][fn], 0, 0, 0);
            }
        // ---- bias + gelu -> H2c (swizzled for A-frag reads) ----
        #pragma unroll
        for (int fm = 0; fm < 2; ++fm)
            #pragma unroll
            for (int fn = 0; fn < 2; ++fn) {
                int coll = wc * 32 + fn * 16 + (lane & 15);
                float bv = b1[it * 64 + coll];
                #pragma unroll
                for (int r = 0; r < 4; ++r) {
                    int rowl = wr * 32 + fm * 16 + ((lane >> 4) << 2) + r;
                    float v = gelu_fast(acc1[fm][fn][r] + bv);
                    H2c[rowl * 64 + (((coll >> 3) ^ (rowl & 7)) << 3) + (coll & 7)] = f2b(v);
                }
            }
        __syncthreads();   // H2c visible

        // ---- fc2 accumulate: K-chunk of 64 ----
        #pragma unroll
        for (int kk = 0; kk < 2; ++kk) {
            int kcq = kk * 4 + (lane >> 4);
            bf16x8 af[2], bfr[6];
            #pragma unroll
            for (int fm = 0; fm < 2; ++fm) {
                int row = wr * 32 + fm * 16 + (lane & 15);
                af[fm] = *(const bf16x8*)&H2c[row * 64 + ((kcq ^ (row & 7)) << 3)];
            }
            #pragma unroll
            for (int fn = 0; fn < 6; ++fn) {
                int row = wc * 96 + fn * 16 + (lane & 15);
                bfr[fn] = *(const bf16x8*)&W2c[row * 64 + ((kcq ^ (row & 7)) << 3)];
            }
            #pragma unroll
            for (int fm = 0; fm < 2; ++fm)
                #pragma unroll
                for (int fn = 0; fn < 6; ++fn)
                    acc2[fm][fn] = __builtin_amdgcn_mfma_f32_16x16x32_bf16(
                        af[fm], bfr[fn], acc2[fm][fn], 0, 0, 0);
        }
    }
    __syncthreads();   // all fc2 reads done before epilogue overwrites W1c/H2c/W2c

    // ---- epilogue: bias + LN partials; values -> VAL[64][200] ----
    #pragma unroll
    for (int fm = 0; fm < 2; ++fm)
        #pragma unroll
        for (int r = 0; r < 4; ++r) {
            int rowl = wr * 32 + fm * 16 + ((lane >> 4) << 2) + r;
            float s = 0.0f, s2 = 0.0f;
            #pragma unroll
            for (int fn = 0; fn < 6; ++fn) {
                int col = wc * 96 + fn * 16 + (lane & 15);
                float v = acc2[fm][fn][r] + b2[col];
                VAL[rowl * 200 + col] = f2b(v);
                s += v; s2 += v * v;
            }
            #pragma unroll
            for (int m = 1; m < 16; m <<= 1) {
                s  += __shfl_xor(s, m);
                s2 += __shfl_xor(s2, m);
            }
            if ((lane & 15) == 0) {
                part[rowl * 4 + wc * 2]     = s;
                part[rowl * 4 + wc * 2 + 1] = s2;
            }
        }
    __syncthreads();

    // ---- copy-out with residual (from As) + window-reverse: 4 threads/row, 48 cols ----
    int row = tid >> 2;
    int cb = (tid & 3) * 48;
    float s  = part[row * 4 + 0] + part[row * 4 + 2];
    float s2 = part[row * 4 + 1] + part[row * 4 + 3];
    float mean = s * (1.0f / 192.0f);
    float rstd = rsqrtf(s2 * (1.0f / 192.0f) - mean * mean + 1e-5f);
    int rw = (int)rb + row;
    int win = rw >> 8, n = rw & 255, b = rw >> 12;
    int wh = (win >> 2) & 3, wwn = win & 3;
    int y  = (wh * 16 + (n >> 4) + SHIFT) & 63;
    int xq = (wwn * 16 + (n & 15) + SHIFT) & 63;
    size_t rimg = (size_t)b * 4096 + y * 64 + xq;
    const float* wt = wtab + 2 * 16 * 192 + b * 192;   // LN2 w table
    const float* bt = wtab + 3 * 16 * 192 + b * 192;   // LN2 b table
    #pragma unroll
    for (int c8 = 0; c8 < 6; ++c8) {
        int c = cb + c8 * 8;
        bf16x8 lv = *(const bf16x8*)&VAL[row * 200 + c];
        // residual from persistent As (swizzled)
        bf16x8 hv = *(const bf16x8*)&As[(c >> 6) * 4096 + row * 64 +
                                        ((((c & 63) >> 3) ^ (row & 7)) << 3)];
        float4 w0 = *(const float4*)&wt[c], w1 = *(const float4*)&wt[c + 4];
        float4 b0 = *(const float4*)&bt[c], b1 = *(const float4*)&bt[c + 4];
        float wv[8] = {w0.x, w0.y, w0.z, w0.w, w1.x, w1.y, w1.z, w1.w};
        float bv[8] = {b0.x, b0.y, b0.z, b0.w, b1.x, b1.y, b1.z, b1.w};
        float4 o0, o1;
        float oo[8];
        #pragma unroll
        for (int e = 0; e < 8; ++e) {
            float xn = (b2f(lv[e]) - mean) * rstd;
            oo[e] = b2f(hv[e]) + wv[e] * xn + bv[e];
        }
        o0.x = oo[0]; o0.y = oo[1]; o0.z = oo[2]; o0.w = oo[3];
        o1.x = oo[4]; o1.y = oo[5]; o1.z = oo[6]; o1.w = oo[7];
        *(float4*)&out[rimg * CC + c] = o0;
        *(float4*)&out[rimg * CC + c + 4] = o1;
    }
}

extern "C" void kernel_launch(void* const* d_in, const int* in_sizes, int n_in,
                              void* d_out, int out_size, void* d_ws, size_t ws_size,
                              hipStream_t stream)
{
    const float* x        = (const float*)d_in[0];
    const float* time     = (const float*)d_in[1];
    const float* q_w      = (const float*)d_in[2];
    const float* q_b      = (const float*)d_in[3];
    const float* k_w      = (const float*)d_in[4];
    const float* v_w      = (const float*)d_in[5];
    const float* v_b      = (const float*)d_in[6];
    const float* lscale   = (const float*)d_in[7];
    const float* cpb_w1   = (const float*)d_in[8];
    const float* cpb_b1   = (const float*)d_in[9];
    const float* cpb_w2   = (const float*)d_in[10];
    const float* proj_w   = (const float*)d_in[11];
    const float* proj_b   = (const float*)d_in[12];
    const float* ln1_ww   = (const float*)d_in[13];
    const float* ln1_wb   = (const float*)d_in[14];
    const float* ln1_bw   = (const float*)d_in[15];
    const float* ln1_bb   = (const float*)d_in[16];
    const float* fc1_w    = (const float*)d_in[17];
    const float* fc1_b    = (const float*)d_in[18];
    const float* fc2_w    = (const float*)d_in[19];
    const float* fc2_b    = (const float*)d_in[20];
    const float* ln2_ww   = (const float*)d_in[21];
    const float* ln2_wb   = (const float*)d_in[22];
    const float* ln2_bw   = (const float*)d_in[23];
    const float* ln2_bb   = (const float*)d_in[24];

    char* ws = (char*)d_ws;
    float* tbl            = (float*)(ws + OFF_TBL);
    __half* biasp         = (__half*)(ws + OFF_BIASM);
    __hip_bfloat16* wqkv  = (__hip_bfloat16*)(ws + OFF_WQKV);
    __hip_bfloat16* pwb   = (__hip_bfloat16*)(ws + OFF_PWB);
    __hip_bfloat16* w1b   = (__hip_bfloat16*)(ws + OFF_W1B);
    __hip_bfloat16* w2b   = (__hip_bfloat16*)(ws + OFF_W2B);
    float* bqkv           = (float*)(ws + OFF_BQKV);
    float* wtab           = (float*)(ws + OFF_WTAB);
    __hip_bfloat16* xb    = (__hip_bfloat16*)(ws + OFF_XB);
    __hip_bfloat16* qb    = (__hip_bfloat16*)(ws + OFF_Q);
    __hip_bfloat16* kb    = (__hip_bfloat16*)(ws + OFF_K);
    __hip_bfloat16* vb    = (__hip_bfloat16*)(ws + OFF_V);
    __hip_bfloat16* ao    = (__hip_bfloat16*)(ws + OFF_AO);
    __hip_bfloat16* hb    = (__hip_bfloat16*)(ws + OFF_HB);   // == xb region
    float* out            = (float*)d_out;

    k_tbl   <<<961, 512, 0, stream>>>(cpb_w1, cpb_b1, cpb_w2, tbl);
    k_biasm <<<4 * NH * NN, 256, 0, stream>>>(tbl, lscale, biasp);
    k_cvt   <<<1731, 256, 0, stream>>>(q_w, k_w, v_w, proj_w, fc1_w, fc2_w,
                                       q_b, v_b, wqkv, pwb, w1b, w2b, bqkv);
    k_wtab  <<<48, 256, 0, stream>>>(time, ln1_ww, ln1_wb, ln1_bw, ln1_bb,
                                     ln2_ww, ln2_wb, ln2_bw, ln2_bb, wtab);
    k_gather<<<12288, 256, 0, stream>>>(x, xb);
    k_qkvgemm<<<dim3(NROWS / 128, 9), 256, 0, stream>>>(xb, wqkv, bqkv, lscale, qb, kb, vb);
    k_attn  <<<NWIN * NH, 256, 0, stream>>>(qb, kb, vb, biasp, ao);
    k_projgemm<<<NROWS / 128, 256, 0, stream>>>(ao, pwb, proj_b, wtab, xb);
    k_mlp   <<<NROWS / 64, 256, 0, stream>>>(hb, w1b, fc1_b, w2b, fc2_b, wtab, out);
}